// Round 14
// baseline (250.539 us; speedup 1.0000x reference)
//
#include <hip/hip_runtime.h>
#include <hip/hip_bf16.h>
#include <math.h>

typedef __bf16 bf16;
typedef __bf16 v8bf __attribute__((ext_vector_type(8)));
typedef __bf16 v4bf __attribute__((ext_vector_type(4)));
typedef float  v4f  __attribute__((ext_vector_type(4)));

#define FDIM 256
#define BSHIFT 7          // bucket = dst >> 7 (128 nodes/bucket, 391 buckets)
#define BKT_CAP 4096      // mean 2558 edges/bucket, cap = +30 sigma
#define AROW 264          // LDS A row stride (528B -> 2-way bank aliasing, free)
#define GEMM_BLOCKS 512
#define P3_BLOCKS 512

// ---------------- utility ----------------

__global__ __launch_bounds__(256) void flag_kernel(float* __restrict__ out, int n) {
  int i = blockIdx.x * 256 + threadIdx.x;
  if (i < n) out[i] = 1.0e9f;
}

// ---------------- K1: W1 transpose + per-block bucket hists + V projection ----
// blocks 0..255: Wt1 transpose; 256..511: per-block hist -> phist; 512: V/cc.
__global__ __launch_bounds__(256) void k1_prep(const float* __restrict__ W1,
                                               const float* __restrict__ W2,
                                               bf16* __restrict__ Wt1,
                                               const int* __restrict__ dst,
                                               int* __restrict__ phist,
                                               const float* __restrict__ Wl,
                                               const float* __restrict__ b2,
                                               const float* __restrict__ bl,
                                               float4* __restrict__ V,
                                               float* __restrict__ cc,
                                               int E, int N) {
  __shared__ int h[512];
  __shared__ float sWl[1024];
  __shared__ float red[256];
  int b = blockIdx.x;
  int t = threadIdx.x;
  if (b < 256) {
    Wt1[t * FDIM + b] = (bf16)W1[b * FDIM + t];
  } else if (b < 512) {
    int pb = b - 256;  // 0..255
    h[t] = 0; h[t + 256] = 0;
    __syncthreads();
    for (int e = pb * 256 + t; e < E; e += 256 * 256) {
      int d = dst[e];
      d = d < 0 ? 0 : (d >= N ? N - 1 : d);
      atomicAdd(&h[d >> BSHIFT], 1);
    }
    __syncthreads();
    phist[pb * 512 + t] = h[t];
    phist[pb * 512 + t + 256] = h[t + 256];
  } else {
    // V[k] = (W2[k]·Wl_top0, W2[k]·Wl_top1, W2[k]·Wl_bot0, W2[k]·Wl_bot1)
#pragma unroll
    for (int j = 0; j < 4; ++j) sWl[j * 256 + t] = Wl[j * 256 + t];
    __syncthreads();
    const float* w2row = W2 + (size_t)t * FDIM;
    float4 acc = make_float4(0.f, 0.f, 0.f, 0.f);
    for (int j = 0; j < 256; ++j) {
      float w = w2row[j];
      acc.x += w * sWl[2 * j + 0];
      acc.y += w * sWl[2 * j + 1];
      acc.z += w * sWl[512 + 2 * j + 0];
      acc.w += w * sWl[512 + 2 * j + 1];
    }
    V[t] = acc;
    float bj = b2[t];
    red[t] = bj * (sWl[2 * t + 0] + sWl[512 + 2 * t + 0]);
    __syncthreads();
    if (t == 0) {
      float s = 0.f;
      for (int j = 0; j < 256; ++j) s += red[j];
      cc[0] = s + bl[0];
    }
    __syncthreads();
    red[t] = bj * (sWl[2 * t + 1] + sWl[512 + 2 * t + 1]);
    __syncthreads();
    if (t == 0) {
      float s = 0.f;
      for (int j = 0; j < 256; ++j) s += red[j];
      cc[1] = s + bl[1];
    }
  }
}

// ---------------- p2: sum per-block hists, scan 512 bins -> bbase/gcur --------
__global__ __launch_bounds__(512) void p2_scan(const int* __restrict__ phist,
                                               int* __restrict__ bbase,
                                               int* __restrict__ gcur,
                                               int* __restrict__ offs,
                                               int nbkt, int Nn) {
  __shared__ int wsum[8];
  int t = threadIdx.x, lane = t & 63, wv = t >> 6;
  int v = 0;
  for (int pb = 0; pb < 256; ++pb) v += phist[pb * 512 + t];
  if (t >= nbkt) v = 0;
  int x = v;
#pragma unroll
  for (int d = 1; d < 64; d <<= 1) {
    int y = __shfl_up(x, d, 64);
    if (lane >= d) x += y;
  }
  if (lane == 63) wsum[wv] = x;
  __syncthreads();
  int woff = 0;
  for (int i = 0; i < wv; ++i) woff += wsum[i];
  int incl = woff + x;
  int excl = incl - v;
  if (t < nbkt) { bbase[t] = excl; gcur[t] = excl; }
  if (t == 511) {        // grand total (v=0 past nbkt)
    bbase[nbkt] = incl;
    offs[Nn] = incl;
  }
}

// ---------------- GEMM v4 body (gemm1 only) ----------------

__device__ inline void stage64(const float* __restrict__ A, bf16* __restrict__ As,
                               int row0, int M, int tid) {
#pragma unroll
  for (int j = 0; j < 8; ++j) {
    int g = j * 2048 + tid * 8;
    int r = g >> 8, c = g & 255;
    int gr = row0 + r; if (gr >= M) gr = M - 1;
    const float* p = A + (size_t)gr * FDIM + c;
    float4 f0 = *reinterpret_cast<const float4*>(p);
    float4 f1 = *reinterpret_cast<const float4*>(p + 4);
    v8bf o;
    o[0] = (bf16)f0.x; o[1] = (bf16)f0.y; o[2] = (bf16)f0.z; o[3] = (bf16)f0.w;
    o[4] = (bf16)f1.x; o[5] = (bf16)f1.y; o[6] = (bf16)f1.z; o[7] = (bf16)f1.w;
    *reinterpret_cast<v8bf*>(As + r * AROW + c) = o;
  }
}

__device__ inline void gemm_body(const float* __restrict__ A, const bf16* __restrict__ Bt,
                                 bf16* __restrict__ C, int M, int bid, int nblocks,
                                 bf16* __restrict__ As) {
  const int K = FDIM, N = FDIM;
  int tid = threadIdx.x;
  int wave = tid >> 6;
  int lane = tid & 63;
  int l15 = lane & 15, quad = lane >> 4;

  v8bf bfr[4][8];
#pragma unroll
  for (int nn = 0; nn < 4; ++nn) {
    const bf16* bp = Bt + (size_t)(wave * 64 + nn * 16 + l15) * K + quad * 8;
#pragma unroll
    for (int kk = 0; kk < 8; ++kk)
      bfr[nn][kk] = *reinterpret_cast<const v8bf*>(bp + kk * 32);
  }

  int ntiles = (M + 63) >> 6;
  for (int tile = bid; tile < ntiles; tile += nblocks) {
    int row0 = tile * 64;
    __syncthreads();
    stage64(A, As, row0, M, tid);
    __syncthreads();

#pragma unroll
    for (int st = 0; st < 4; ++st) {
      v8bf afr[8];
#pragma unroll
      for (int kk = 0; kk < 8; ++kk)
        afr[kk] = *reinterpret_cast<const v8bf*>(As + (st * 16 + l15) * AROW + quad * 8 + kk * 32);

      v4f acc[4];
#pragma unroll
      for (int nn = 0; nn < 4; ++nn) acc[nn] = (v4f){0.f, 0.f, 0.f, 0.f};

#pragma unroll
      for (int kk = 0; kk < 8; ++kk)
#pragma unroll
        for (int nn = 0; nn < 4; ++nn)
          acc[nn] = __builtin_amdgcn_mfma_f32_16x16x32_bf16(afr[kk], bfr[nn][kk], acc[nn], 0, 0, 0);

#pragma unroll
      for (int nn = 0; nn < 4; ++nn)
#pragma unroll
        for (int r = 0; r < 4; ++r) {
          int row = row0 + st * 16 + quad * 4 + r;
          int col = wave * 64 + nn * 16 + l15;
          if (row < M) C[(size_t)row * N + col] = (bf16)acc[nn][r];
        }
    }
  }
}

// ---------------- p3 body: LDS-binned scatter into 512 bucket regions ----------
__device__ inline void p3_body(const int* __restrict__ src, const int* __restrict__ dst,
                               const float* __restrict__ ew, int* __restrict__ gcur,
                               uint2* __restrict__ tmp, int E, int N, int nbkt,
                               int pb, int nblocks, int* h, int* base, int* cnt) {
  int t = threadIdx.x;
  int chunk = (E + nblocks - 1) / nblocks;
  int lo = pb * chunk;
  int hi = lo + chunk; if (hi > E) hi = E;
  h[t] = 0; h[t + 256] = 0; cnt[t] = 0; cnt[t + 256] = 0;
  __syncthreads();
  for (int e = lo + t; e < hi; e += 256) {
    int d = dst[e];
    d = d < 0 ? 0 : (d >= N ? N - 1 : d);
    atomicAdd(&h[d >> BSHIFT], 1);
  }
  __syncthreads();
  for (int b = t; b < nbkt; b += 256)
    if (h[b]) base[b] = atomicAdd(&gcur[b], h[b]);
  __syncthreads();
  for (int e = lo + t; e < hi; e += 256) {
    int d = dst[e];
    d = d < 0 ? 0 : (d >= N ? N - 1 : d);
    int b = d >> BSHIFT;
    int sv = src[e];
    sv = sv < 0 ? 0 : (sv >= N ? N - 1 : sv);
    unsigned int u = __float_as_uint(ew[e]);
    unsigned int wbits = ((u + 0x7FFFu + ((u >> 16) & 1u)) & 0xFFFF0000u);  // RN bf16
    unsigned int meta = wbits | (unsigned int)(sv & 0xFFFF);
    int r = atomicAdd(&cnt[b], 1);
    int pos = base[b] + r;
    if (pos >= 0 && pos < E) tmp[pos] = make_uint2(meta, (unsigned int)d);
  }
}

// ---------------- K3: gemm1 (0..511) + p3 (512..1023) ----------------
__global__ __launch_bounds__(256, 2) void k3_gemm1_p3(const float* __restrict__ x,
                                                      const bf16* __restrict__ Wt1,
                                                      bf16* __restrict__ bufT, int M,
                                                      const int* __restrict__ src,
                                                      const int* __restrict__ dst,
                                                      const float* __restrict__ ew,
                                                      int* __restrict__ gcur,
                                                      uint2* __restrict__ tmp,
                                                      int E, int N, int nbkt) {
  __shared__ bf16 As[64 * AROW];
  __shared__ int h[512], base[512], cnt[512];
  if (blockIdx.x < GEMM_BLOCKS)
    gemm_body(x, Wt1, bufT, M, blockIdx.x, GEMM_BLOCKS, As);
  else
    p3_body(src, dst, ew, gcur, tmp, E, N, nbkt,
            blockIdx.x - GEMM_BLOCKS, P3_BLOCKS, h, base, cnt);
}

// ---------------- p4: per-bucket (128 nodes) LDS count-sort ----------------
__global__ __launch_bounds__(256) void p4_sort(const uint2* __restrict__ tmp,
                                               const int* __restrict__ bbase,
                                               unsigned int* __restrict__ pmeta,
                                               int* __restrict__ offs,
                                               int Nn, int E) {
  __shared__ uint2 ent[BKT_CAP];
  __shared__ int h2[128], ex2[128], c2[128];
  __shared__ int wsum[4];
  int b = blockIdx.x, t = threadIdx.x, lane = t & 63, wv = t >> 6;
  int s0 = bbase[b], s1 = bbase[b + 1];
  int count = s1 - s0;
  if (count < 0) count = 0;
  if (count > BKT_CAP) count = BKT_CAP;
  for (int i = t; i < count; i += 256) ent[i] = tmp[s0 + i];
  if (t < 128) { h2[t] = 0; c2[t] = 0; }
  __syncthreads();
  for (int i = t; i < count; i += 256) atomicAdd(&h2[ent[i].y & 127u], 1);
  __syncthreads();
  int v = (t < 128) ? h2[t] : 0;
  int x = v;
#pragma unroll
  for (int d = 1; d < 64; d <<= 1) {
    int y = __shfl_up(x, d, 64);
    if (lane >= d) x += y;
  }
  if (lane == 63) wsum[wv] = x;
  __syncthreads();
  int woff = 0;
  if (wv >= 1) woff += wsum[0];
  if (wv >= 2) woff += wsum[1];
  if (wv >= 3) woff += wsum[2];
  int excl = woff + x - v;
  if (t < 128) {
    ex2[t] = excl;
    int node = (b << BSHIFT) + t;
    if (node < Nn) offs[node] = s0 + excl;
  }
  __syncthreads();
  for (int i = t; i < count; i += 256) {
    int l = (int)(ent[i].y & 127u);
    int r = atomicAdd(&c2[l], 1);
    int pos = s0 + ex2[l] + r;
    if (pos >= 0 && pos < E) pmeta[pos] = ent[i].x;
  }
}

// ---------------- agg1G: G[n] = relu(agg(t1)+b1) @ V  (h1 never materialized) --
__global__ __launch_bounds__(256) void agg1G(const bf16* __restrict__ T,
                                             const unsigned int* __restrict__ pmeta,
                                             const int* __restrict__ offsets,
                                             const float* __restrict__ bias,
                                             const float4* __restrict__ V,
                                             float4* __restrict__ G, int N, int E) {
  int node = blockIdx.x * 4 + (threadIdx.x >> 6);
  if (node >= N) return;
  int lane = threadIdx.x & 63;
  int f = lane * 4;
  int beg = offsets[node], end = offsets[node + 1];
  beg = beg < 0 ? 0 : (beg > E ? E : beg);
  end = end < beg ? beg : (end > E ? E : end);
  const unsigned int* m = pmeta + beg;
  int cnt = end - beg;

  float a0 = 0.f, a1 = 0.f, a2 = 0.f, a3 = 0.f;
  int p = 0;
  for (; p + 8 <= cnt; p += 8) {
    unsigned int mv[8];
#pragma unroll
    for (int j = 0; j < 8; ++j) mv[j] = m[p + j];
    v4bf tv[8];
#pragma unroll
    for (int j = 0; j < 8; ++j) {
      int s = (int)(mv[j] & 0xFFFFu);
      s = s >= N ? N - 1 : s;
      tv[j] = *reinterpret_cast<const v4bf*>(T + (size_t)s * FDIM + f);
    }
#pragma unroll
    for (int j = 0; j < 8; ++j) {
      float w = __uint_as_float(mv[j] & 0xFFFF0000u);
      a0 += w * (float)tv[j][0];
      a1 += w * (float)tv[j][1];
      a2 += w * (float)tv[j][2];
      a3 += w * (float)tv[j][3];
    }
  }
  for (; p < cnt; ++p) {
    unsigned int mv = m[p];
    int s = (int)(mv & 0xFFFFu);
    s = s >= N ? N - 1 : s;
    float w = __uint_as_float(mv & 0xFFFF0000u);
    v4bf tv = *reinterpret_cast<const v4bf*>(T + (size_t)s * FDIM + f);
    a0 += w * (float)tv[0];
    a1 += w * (float)tv[1];
    a2 += w * (float)tv[2];
    a3 += w * (float)tv[3];
  }
  a0 = fmaxf(a0 + bias[f + 0], 0.f);
  a1 = fmaxf(a1 + bias[f + 1], 0.f);
  a2 = fmaxf(a2 + bias[f + 2], 0.f);
  a3 = fmaxf(a3 + bias[f + 3], 0.f);

  float4 v0 = V[f + 0], v1 = V[f + 1], v2 = V[f + 2], v3 = V[f + 3];
  float gx = a0 * v0.x + a1 * v1.x + a2 * v2.x + a3 * v3.x;
  float gy = a0 * v0.y + a1 * v1.y + a2 * v2.y + a3 * v3.y;
  float gz = a0 * v0.z + a1 * v1.z + a2 * v2.z + a3 * v3.z;
  float gw = a0 * v0.w + a1 * v1.w + a2 * v2.w + a3 * v3.w;
#pragma unroll
  for (int d = 32; d > 0; d >>= 1) {
    gx += __shfl_down(gx, d, 64);
    gy += __shfl_down(gy, d, 64);
    gz += __shfl_down(gz, d, 64);
    gw += __shfl_down(gw, d, 64);
  }
  if (lane == 0) G[node] = make_float4(gx, gy, gz, gw);
}

// ---------------- aggP (wave-ified): P[n] = sum_e w_e G[src_e] ----------------
// 16 lanes per node gather in parallel; shfl_xor reduce within 16-lane groups.
__global__ __launch_bounds__(256) void aggP(const float4* __restrict__ G,
                                            const unsigned int* __restrict__ pmeta,
                                            const int* __restrict__ offsets,
                                            float4* __restrict__ P, int N, int E) {
  int tid = threadIdx.x;
  int wave = tid >> 6, lane = tid & 63;
  int grp = lane >> 4, sub = lane & 15;
  int node = blockIdx.x * 16 + wave * 4 + grp;
  if (node >= N) return;
  int beg = offsets[node], end = offsets[node + 1];
  beg = beg < 0 ? 0 : (beg > E ? E : beg);
  end = end < beg ? beg : (end > E ? E : end);
  float ax = 0.f, ay = 0.f, az = 0.f, aw = 0.f;
  for (int p = beg + sub; p < end; p += 16) {
    unsigned int mm = pmeta[p];
    int s = (int)(mm & 0xFFFFu); s = s >= N ? N - 1 : s;
    float w = __uint_as_float(mm & 0xFFFF0000u);
    float4 g = G[s];
    ax += w * g.x; ay += w * g.y; az += w * g.z; aw += w * g.w;
  }
#pragma unroll
  for (int d = 1; d < 16; d <<= 1) {
    ax += __shfl_xor(ax, d, 64);
    ay += __shfl_xor(ay, d, 64);
    az += __shfl_xor(az, d, 64);
    aw += __shfl_xor(aw, d, 64);
  }
  if (sub == 0) P[node] = make_float4(ax, ay, az, aw);
}

// ---------------- query: logits from P + cc, log-softmax ----------------
__global__ __launch_bounds__(256) void query_small(const int* __restrict__ qe,
                                                   const float4* __restrict__ P,
                                                   const float* __restrict__ cc,
                                                   float* __restrict__ out, int Q, int N) {
  int q = blockIdx.x * 256 + threadIdx.x;
  if (q >= Q) return;
  int n0 = qe[2 * q + 0]; n0 = n0 < 0 ? 0 : (n0 >= N ? N - 1 : n0);
  int n1 = qe[2 * q + 1]; n1 = n1 < 0 ? 0 : (n1 >= N ? N - 1 : n1);
  float4 p0 = P[n0];
  float4 p1 = P[n1];
  float l0 = p0.x + p1.z + cc[0];
  float l1 = p0.y + p1.w + cc[1];
  float m = fmaxf(l0, l1);
  float lse = m + logf(expf(l0 - m) + expf(l1 - m));
  out[2 * q + 0] = l0 - lse;
  out[2 * q + 1] = l1 - lse;
}

// ---------------- host launcher ----------------

extern "C" void kernel_launch(void* const* d_in, const int* in_sizes, int n_in,
                              void* d_out, int out_size, void* d_ws, size_t ws_size,
                              hipStream_t stream) {
  const float* x  = (const float*)d_in[0];
  const int*   ei = (const int*)d_in[1];
  const int*   qe = (const int*)d_in[2];
  const float* ew = (const float*)d_in[3];
  const float* W1 = (const float*)d_in[4];
  const float* b1 = (const float*)d_in[5];
  const float* W2 = (const float*)d_in[6];
  const float* b2 = (const float*)d_in[7];
  const float* Wl = (const float*)d_in[8];
  const float* bl = (const float*)d_in[9];

  int N = in_sizes[0] / FDIM;  // 50000
  int E = in_sizes[1] / 2;     // 1,000,000
  int Q = in_sizes[2] / 2;     // 100,000
  const int* srcv = ei;
  const int* dstv = ei + E;
  int nbkt = (N + 127) >> BSHIFT;  // 391

  size_t off = 0;
  auto alloc = [&](size_t bytes) -> void* {
    void* p = (char*)d_ws + off;
    off += (bytes + 255) & ~(size_t)255;
    return p;
  };
  bf16* bufT  = (bf16*)alloc((size_t)N * FDIM * 2);   // t1 = x@W1
  uint2* tmp  = (uint2*)alloc((size_t)E * 8);         // bucket-scattered {meta,dst}
  bf16* Wt1   = (bf16*)alloc((size_t)FDIM * FDIM * 2);
  int* offs   = (int*)alloc((size_t)(N + 1) * 4);
  unsigned int* pmeta = (unsigned int*)alloc((size_t)E * 4);
  float4* G   = (float4*)alloc((size_t)N * 16);
  float4* P   = (float4*)alloc((size_t)N * 16);
  float4* V   = (float4*)alloc(256 * 16);
  float* cc   = (float*)alloc(2 * 4);
  int* phist  = (int*)alloc(256 * 512 * 4);
  int* bbase  = (int*)alloc(512 * 4);
  int* gcur   = (int*)alloc(512 * 4);

  if (off > ws_size) {
    flag_kernel<<<(out_size + 255) / 256, 256, 0, stream>>>((float*)d_out, out_size);
    return;
  }

  // K1: W1 transpose + per-block hists + V/cc (all independent)
  k1_prep<<<513, 256, 0, stream>>>(W1, W2, Wt1, dstv, phist, Wl, b2, bl, V, cc, E, N);
  p2_scan<<<1, 512, 0, stream>>>(phist, bbase, gcur, offs, nbkt, N);
  // K3: gemm1 (t1 = x@W1) overlapped with p3 edge scatter
  k3_gemm1_p3<<<GEMM_BLOCKS + P3_BLOCKS, 256, 0, stream>>>(x, Wt1, bufT, N,
                                                           srcv, dstv, ew, gcur, tmp,
                                                           E, N, nbkt);
  p4_sort<<<nbkt, 256, 0, stream>>>(tmp, bbase, pmeta, offs, N, E);

  // layer 1 + layer-2 collapse: G[n] = relu(agg(t1)+b1) @ V
  agg1G<<<(N + 3) / 4, 256, 0, stream>>>(bufT, pmeta, offs, b1, V, G, N, E);

  // layer 2 aggregation in 4-dim space
  aggP<<<(N + 15) / 16, 256, 0, stream>>>(G, pmeta, offs, P, N, E);

  // per-query combine + log-softmax
  query_small<<<(Q + 255) / 256, 256, 0, stream>>>(qe, P, cc, (float*)d_out, Q, N);
}